// Round 8
// baseline (1986.556 us; speedup 1.0000x reference)
//
#include <hip/hip_runtime.h>

#define NT 1024

typedef _Float16 half8 __attribute__((ext_vector_type(8)));
typedef _Float16 half4 __attribute__((ext_vector_type(4)));
typedef float f32x4 __attribute__((ext_vector_type(4)));
typedef unsigned long long u64;

__device__ __forceinline__ f32x4 MFMA(half8 a, half8 b, f32x4 c) {
  return __builtin_amdgcn_mfma_f32_16x16x32_f16(a, b, c, 0, 0, 0);
}
__device__ __forceinline__ float sigf(float x) {
  return __builtin_amdgcn_rcpf(1.0f + __expf(-x));
}
__device__ __forceinline__ float tanhf2(float x) {
  float ax = fabsf(x);
  float e = __expf(-2.0f * ax);
  float t = (1.0f - e) * __builtin_amdgcn_rcpf(1.0f + e);
  return copysignf(t, x);
}
__device__ __forceinline__ half8 cvt8(float4 c0, float4 c1) {
  half8 hv;
  hv[0] = (_Float16)c0.x; hv[1] = (_Float16)c0.y;
  hv[2] = (_Float16)c0.z; hv[3] = (_Float16)c0.w;
  hv[4] = (_Float16)c1.x; hv[5] = (_Float16)c1.y;
  hv[6] = (_Float16)c1.z; hv[7] = (_Float16)c1.w;
  return hv;
}

// Repack x [B,T,64] f32 -> f16 B-fragments Xf[g][t][kt][lane][8]
// k-perm within tile: kk(lane,j) = (j>>2)*16 + (lane>>4)*4 + (j&3)
__global__ __launch_bounds__(256) void prep_x(const float* __restrict__ x,
                                              _Float16* __restrict__ Xf) {
  int t0 = blockIdx.x * 256 + threadIdx.x;
  int l = t0 & 63;
  int fid = t0 >> 6;                  // ((g*NT + t)*2 + kt)
  int kt = fid & 1;
  int t = (fid >> 1) & (NT - 1);
  int g = fid >> 11;
  int bt = g * 16 + (l & 15);
  int kb = kt * 32 + (l >> 4) * 4;
  const float* src = x + ((size_t)bt * NT + (size_t)t) * 64 + kb;
  float4 v0 = *(const float4*)src;
  float4 v1 = *(const float4*)(src + 16);
  *(half8*)(Xf + (size_t)fid * 512 + l * 8) = cvt8(v0, v1);
}

// ---------------- Layer 0: 8 blocks, group g = 16 batch rows ----------------
// Per step: 24 MFMA/wave (x 2kt + h0 4kt), cell, h0 frag -> global (plain
// stores, no drain; kernel boundary is the sync). 1 lgkm-only barrier/step.
__global__ __launch_bounds__(512, 1) void lstm_l0(
    const float* __restrict__ wih0, const float* __restrict__ whh0,
    const float* __restrict__ bih, const float* __restrict__ bhh,
    const _Float16* __restrict__ Xf, _Float16* __restrict__ h0f) {
  const int tid = threadIdx.x;
  const int w = tid >> 6, l = tid & 63;
  const int n = l & 15, lg = l >> 4;
  const int g = blockIdx.x;

  __shared__ _Float16 hfr[2][4][64][8];
  const half8 hz = {0, 0, 0, 0, 0, 0, 0, 0};

  half8 A[4][6];
  f32x4 bias[4];
#pragma unroll
  for (int q = 0; q < 4; ++q) {
    int row = (w + 8 * q) * 16 + n;
#pragma unroll
    for (int kt = 0; kt < 2; ++kt) {
      const float* wp = wih0 + (size_t)row * 64 + kt * 32 + lg * 4;
      A[q][kt] = cvt8(*(const float4*)wp, *(const float4*)(wp + 16));
    }
#pragma unroll
    for (int kt = 0; kt < 4; ++kt) {
      const float* wp = whh0 + (size_t)row * 128 + kt * 32 + lg * 4;
      A[q][2 + kt] = cvt8(*(const float4*)wp, *(const float4*)(wp + 16));
    }
    int rb = (w + 8 * q) * 16 + lg * 4;
    f32x4 bv;
#pragma unroll
    for (int r = 0; r < 4; ++r) bv[r] = bih[rb + r] + bhh[rb + r];
    bias[q] = bv;
  }
  if (tid < 256) ((half8*)&hfr[1][0][0][0])[tid] = hz;  // h0[-1]=0
  const _Float16* XfG = Xf + (size_t)g * NT * 1024;
  _Float16* h0G = h0f + (size_t)g * NT * 2048;
  half8 x0 = *(const half8*)(XfG + l * 8);
  half8 x1 = *(const half8*)(XfG + 512 + l * 8);
  f32x4 cst = {0.f, 0.f, 0.f, 0.f};
  __syncthreads();
  for (int s = 0; s < NT; ++s) {
    half8 xn0, xn1;
    if (s + 1 < NT) {
      const _Float16* p = XfG + (size_t)(s + 1) * 1024 + l * 8;
      xn0 = *(const half8*)p;
      xn1 = *(const half8*)(p + 512);
    }
    const int rdk = (s + 1) & 1;
    half8 b2 = *(const half8*)&hfr[rdk][0][l][0];
    half8 b3 = *(const half8*)&hfr[rdk][1][l][0];
    half8 b4 = *(const half8*)&hfr[rdk][2][l][0];
    half8 b5 = *(const half8*)&hfr[rdk][3][l][0];
    f32x4 acc0 = bias[0], acc1 = bias[1], acc2 = bias[2], acc3 = bias[3];
    acc0 = MFMA(A[0][0], x0, acc0); acc1 = MFMA(A[1][0], x0, acc1);
    acc2 = MFMA(A[2][0], x0, acc2); acc3 = MFMA(A[3][0], x0, acc3);
    acc0 = MFMA(A[0][1], x1, acc0); acc1 = MFMA(A[1][1], x1, acc1);
    acc2 = MFMA(A[2][1], x1, acc2); acc3 = MFMA(A[3][1], x1, acc3);
    acc0 = MFMA(A[0][2], b2, acc0); acc1 = MFMA(A[1][2], b2, acc1);
    acc2 = MFMA(A[2][2], b2, acc2); acc3 = MFMA(A[3][2], b2, acc3);
    acc0 = MFMA(A[0][3], b3, acc0); acc1 = MFMA(A[1][3], b3, acc1);
    acc2 = MFMA(A[2][3], b3, acc2); acc3 = MFMA(A[3][3], b3, acc3);
    acc0 = MFMA(A[0][4], b4, acc0); acc1 = MFMA(A[1][4], b4, acc1);
    acc2 = MFMA(A[2][4], b4, acc2); acc3 = MFMA(A[3][4], b4, acc3);
    acc0 = MFMA(A[0][5], b5, acc0); acc1 = MFMA(A[1][5], b5, acc1);
    acc2 = MFMA(A[2][5], b5, acc2); acc3 = MFMA(A[3][5], b5, acc3);
    half4 hh;
#pragma unroll
    for (int r = 0; r < 4; ++r) {
      float iv = sigf(acc0[r]), fv = sigf(acc1[r]);
      float gv = tanhf2(acc2[r]), ov = sigf(acc3[r]);
      cst[r] = fv * cst[r] + iv * gv;
      hh[r] = (_Float16)(ov * tanhf2(cst[r]));
    }
    *(half4*)&hfr[s & 1][w >> 1][l][(w & 1) << 2] = hh;
    // plain global store of the frag (fire-and-forget; drained at kernel end)
    *(u64*)(h0G + (size_t)s * 2048 + (w >> 1) * 512 + l * 8 + (w & 1) * 4) =
        __builtin_bit_cast(u64, hh);
    asm volatile("s_waitcnt lgkmcnt(0)" ::: "memory");
    __builtin_amdgcn_sched_barrier(0);
    __builtin_amdgcn_s_barrier();   // vm ops (stores, x prefetch) in flight
    __builtin_amdgcn_sched_barrier(0);
    x0 = xn0;
    x1 = xn1;
  }
}

// ------------- Layer 1 + FC: 8 blocks; h0 frags via plain loads -------------
__global__ __launch_bounds__(512, 1) void lstm_l1(
    const float* __restrict__ wih1, const float* __restrict__ whh1,
    const float* __restrict__ bih, const float* __restrict__ bhh,
    const float* __restrict__ fcw, const float* __restrict__ fcb,
    const _Float16* __restrict__ h0f, float* __restrict__ out) {
  const int tid = threadIdx.x;
  const int w = tid >> 6, l = tid & 63;
  const int n = l & 15, lg = l >> 4;
  const int g = blockIdx.x;

  __shared__ _Float16 hfr[2][4][64][8];
  __shared__ _Float16 fcl[4][4][64][8];
  const half8 hz = {0, 0, 0, 0, 0, 0, 0, 0};

  half8 A[4][8];
  f32x4 bias[4], fcbv = {0.f, 0.f, 0.f, 0.f};
#pragma unroll
  for (int q = 0; q < 4; ++q) {
    int row = (w + 8 * q) * 16 + n;
#pragma unroll
    for (int kt = 0; kt < 4; ++kt) {
      const float* wp = wih1 + (size_t)row * 128 + kt * 32 + lg * 4;
      A[q][kt] = cvt8(*(const float4*)wp, *(const float4*)(wp + 16));
    }
#pragma unroll
    for (int kt = 0; kt < 4; ++kt) {
      const float* wp = whh1 + (size_t)row * 128 + kt * 32 + lg * 4;
      A[q][4 + kt] = cvt8(*(const float4*)wp, *(const float4*)(wp + 16));
    }
    int rb = (w + 8 * q) * 16 + lg * 4;
    f32x4 bv;
#pragma unroll
    for (int r = 0; r < 4; ++r)
      bv[r] = bih[512 + rb + r] + bhh[512 + rb + r];
    bias[q] = bv;
  }
  if (w < 4) {  // FC A-frags -> LDS
    int frow = (w << 4) + n;
#pragma unroll
    for (int kt = 0; kt < 4; ++kt) {
      const float* wp = fcw + (size_t)frow * 128 + kt * 32 + lg * 4;
      *(half8*)&fcl[w][kt][l][0] =
          cvt8(*(const float4*)wp, *(const float4*)(wp + 16));
    }
    fcbv = *(const f32x4*)(fcb + (w << 4) + lg * 4);
  }
  if (tid < 256) ((half8*)&hfr[1][0][0][0])[tid] = hz;  // h1[-1]=0
  const _Float16* h0G = h0f + (size_t)g * NT * 2048;
  float* outG = out + (size_t)((g << 4) + n) * NT * 64 + (w << 4) + lg * 4;
  f32x4 cst = {0.f, 0.f, 0.f, 0.f};
  __syncthreads();
  half8 hA0 = *(const half8*)(h0G + l * 8);
  half8 hA1 = *(const half8*)(h0G + 512 + l * 8);
  half8 hA2 = *(const half8*)(h0G + 1024 + l * 8);
  half8 hA3 = *(const half8*)(h0G + 1536 + l * 8);
  const _Float16* h1p = h0G + 2048 + l * 8;
  half8 hB0 = *(const half8*)(h1p);
  half8 hB1 = *(const half8*)(h1p + 512);
  half8 hB2 = *(const half8*)(h1p + 1024);
  half8 hB3 = *(const half8*)(h1p + 1536);

#define CSTEP(T, C0, C1, C2, C3)                                               \
  {                                                                            \
    const int rdk_ = ((T) + 1) & 1;                                            \
    half8 b4 = *(const half8*)&hfr[rdk_][0][l][0];                             \
    half8 b5 = *(const half8*)&hfr[rdk_][1][l][0];                             \
    half8 b6 = *(const half8*)&hfr[rdk_][2][l][0];                             \
    half8 b7 = *(const half8*)&hfr[rdk_][3][l][0];                             \
    f32x4 acc0 = bias[0], acc1 = bias[1], acc2 = bias[2], acc3 = bias[3];      \
    acc0 = MFMA(A[0][0], C0, acc0); acc1 = MFMA(A[1][0], C0, acc1);            \
    acc2 = MFMA(A[2][0], C0, acc2); acc3 = MFMA(A[3][0], C0, acc3);            \
    acc0 = MFMA(A[0][1], C1, acc0); acc1 = MFMA(A[1][1], C1, acc1);            \
    acc2 = MFMA(A[2][1], C1, acc2); acc3 = MFMA(A[3][1], C1, acc3);            \
    acc0 = MFMA(A[0][2], C2, acc0); acc1 = MFMA(A[1][2], C2, acc1);            \
    acc2 = MFMA(A[2][2], C2, acc2); acc3 = MFMA(A[3][2], C2, acc3);            \
    acc0 = MFMA(A[0][3], C3, acc0); acc1 = MFMA(A[1][3], C3, acc1);            \
    acc2 = MFMA(A[2][3], C3, acc2); acc3 = MFMA(A[3][3], C3, acc3);            \
    if ((T) + 2 < NT) { /* depth-2 prefetch: plain loads, fly over barrier */  \
      const _Float16* hp_ = h0G + (size_t)((T) + 2) * 2048 + l * 8;            \
      C0 = *(const half8*)(hp_);                                               \
      C1 = *(const half8*)(hp_ + 512);                                         \
      C2 = *(const half8*)(hp_ + 1024);                                        \
      C3 = *(const half8*)(hp_ + 1536);                                        \
    }                                                                          \
    acc0 = MFMA(A[0][4], b4, acc0); acc1 = MFMA(A[1][4], b4, acc1);            \
    acc2 = MFMA(A[2][4], b4, acc2); acc3 = MFMA(A[3][4], b4, acc3);            \
    acc0 = MFMA(A[0][5], b5, acc0); acc1 = MFMA(A[1][5], b5, acc1);            \
    acc2 = MFMA(A[2][5], b5, acc2); acc3 = MFMA(A[3][5], b5, acc3);            \
    acc0 = MFMA(A[0][6], b6, acc0); acc1 = MFMA(A[1][6], b6, acc1);            \
    acc2 = MFMA(A[2][6], b6, acc2); acc3 = MFMA(A[3][6], b6, acc3);            \
    acc0 = MFMA(A[0][7], b7, acc0); acc1 = MFMA(A[1][7], b7, acc1);            \
    acc2 = MFMA(A[2][7], b7, acc2); acc3 = MFMA(A[3][7], b7, acc3);            \
    if (w < 4) { /* FC of h1[T-1] on same operands */                          \
      half8 f0 = *(const half8*)&fcl[w][0][l][0];                              \
      half8 f1 = *(const half8*)&fcl[w][1][l][0];                              \
      half8 f2 = *(const half8*)&fcl[w][2][l][0];                              \
      half8 f3 = *(const half8*)&fcl[w][3][l][0];                              \
      f32x4 afc = fcbv;                                                        \
      afc = MFMA(f0, b4, afc); afc = MFMA(f1, b5, afc);                        \
      afc = MFMA(f2, b6, afc); afc = MFMA(f3, b7, afc);                        \
      if ((T) >= 1) *(f32x4*)(outG + (size_t)((T) - 1) * 64) = afc;            \
    }                                                                          \
    half4 hh;                                                                  \
    _Pragma("unroll")                                                          \
    for (int r = 0; r < 4; ++r) {                                              \
      float iv = sigf(acc0[r]), fv = sigf(acc1[r]);                            \
      float gv = tanhf2(acc2[r]), ov = sigf(acc3[r]);                          \
      cst[r] = fv * cst[r] + iv * gv;                                          \
      hh[r] = (_Float16)(ov * tanhf2(cst[r]));                                 \
    }                                                                          \
    *(half4*)&hfr[(T) & 1][w >> 1][l][(w & 1) << 2] = hh;                      \
    asm volatile("s_waitcnt lgkmcnt(0)" ::: "memory");                         \
    __builtin_amdgcn_sched_barrier(0);                                         \
    __builtin_amdgcn_s_barrier(); /* h0 prefetch stays in flight */            \
    __builtin_amdgcn_sched_barrier(0);                                         \
  }

  for (int t = 0; t < NT; t += 2) {
    CSTEP(t, hA0, hA1, hA2, hA3);
    CSTEP(t + 1, hB0, hB1, hB2, hB3);
  }
#undef CSTEP
  {  // epilogue: FC of h1[NT-1] -> out[NT-1]
    half8 b4 = *(const half8*)&hfr[(NT + 1) & 1][0][l][0];
    half8 b5 = *(const half8*)&hfr[(NT + 1) & 1][1][l][0];
    half8 b6 = *(const half8*)&hfr[(NT + 1) & 1][2][l][0];
    half8 b7 = *(const half8*)&hfr[(NT + 1) & 1][3][l][0];
    if (w < 4) {
      half8 f0 = *(const half8*)&fcl[w][0][l][0];
      half8 f1 = *(const half8*)&fcl[w][1][l][0];
      half8 f2 = *(const half8*)&fcl[w][2][l][0];
      half8 f3 = *(const half8*)&fcl[w][3][l][0];
      f32x4 afc = fcbv;
      afc = MFMA(f0, b4, afc); afc = MFMA(f1, b5, afc);
      afc = MFMA(f2, b6, afc); afc = MFMA(f3, b7, afc);
      *(f32x4*)(outG + (size_t)(NT - 1) * 64) = afc;
    }
  }
}

extern "C" void kernel_launch(void* const* d_in, const int* in_sizes, int n_in,
                              void* d_out, int out_size, void* d_ws, size_t ws_size,
                              hipStream_t stream) {
  const float* x     = (const float*)d_in[0];
  const float* w_ih0 = (const float*)d_in[1];
  const float* w_hh0 = (const float*)d_in[2];
  const float* w_ih1 = (const float*)d_in[3];
  const float* w_hh1 = (const float*)d_in[4];
  const float* b_ih  = (const float*)d_in[5];
  const float* b_hh  = (const float*)d_in[6];
  const float* fc_w  = (const float*)d_in[7];
  const float* fc_b  = (const float*)d_in[8];

  _Float16* Xf  = (_Float16*)d_ws;                          // 16 MB
  _Float16* h0f = (_Float16*)((char*)d_ws + (16u << 20));   // 32 MB

  prep_x<<<4096, 256, 0, stream>>>(x, Xf);
  lstm_l0<<<8, 512, 0, stream>>>(w_ih0, w_hh0, b_ih, b_hh, Xf, h0f);
  lstm_l1<<<8, 512, 0, stream>>>(w_ih1, w_hh1, b_ih, b_hh, fc_w, fc_b, h0f,
                                 (float*)d_out);
}

// Round 9
// 1337.218 us; speedup vs baseline: 1.4856x; 1.4856x over previous
//
#include <hip/hip_runtime.h>

#define NT 1024
#define RINGS 256

typedef _Float16 half8 __attribute__((ext_vector_type(8)));
typedef _Float16 half4 __attribute__((ext_vector_type(4)));
typedef float f32x4 __attribute__((ext_vector_type(4)));
typedef unsigned long long u64;
struct U2 { u64 a, b; };

#ifndef __has_builtin
#define __has_builtin(x) 0
#endif

__device__ __forceinline__ f32x4 MFMA(half8 a, half8 b, f32x4 c) {
  return __builtin_amdgcn_mfma_f32_16x16x32_f16(a, b, c, 0, 0, 0);
}
__device__ __forceinline__ float exp2h(float x) {
#if __has_builtin(__builtin_amdgcn_exp2f)
  return __builtin_amdgcn_exp2f(x);
#else
  return exp2f(x);
#endif
}
// sigmoid(x) = rcp(1 + 2^(-1.4427 x))   [mul, exp2, add, rcp]
__device__ __forceinline__ float sigf(float x) {
  return __builtin_amdgcn_rcpf(1.0f + exp2h(x * -1.44269504f));
}
// tanh(x) = 1 - 2*rcp(1 + 2^(2.8854 x))  [mul, exp2, add, rcp, fma]
// saturates naturally: x->+inf => 1, x->-inf => -1
__device__ __forceinline__ float tanhf2(float x) {
  float t = __builtin_amdgcn_rcpf(1.0f + exp2h(x * 2.88539008f));
  return fmaf(-2.0f, t, 1.0f);
}
__device__ __forceinline__ half8 cvt8(float4 c0, float4 c1) {
  half8 hv;
  hv[0] = (_Float16)c0.x; hv[1] = (_Float16)c0.y;
  hv[2] = (_Float16)c0.z; hv[3] = (_Float16)c0.w;
  hv[4] = (_Float16)c1.x; hv[5] = (_Float16)c1.y;
  hv[6] = (_Float16)c1.z; hv[7] = (_Float16)c1.w;
  return hv;
}
__device__ __forceinline__ half8 ldring(const _Float16* p) {
  const u64* q = (const u64*)p;
  U2 uu;
  uu.a = __hip_atomic_load(q, __ATOMIC_RELAXED, __HIP_MEMORY_SCOPE_AGENT);
  uu.b = __hip_atomic_load(q + 1, __ATOMIC_RELAXED, __HIP_MEMORY_SCOPE_AGENT);
  return __builtin_bit_cast(half8, uu);
}
__device__ __forceinline__ unsigned wpoll(unsigned* p, unsigned tgt,
                                          unsigned cached, int l) {
  unsigned c = cached;
  while (c < tgt) {
    unsigned pv = 0;
    if (l == 0)
      pv = __hip_atomic_load(p, __ATOMIC_ACQUIRE, __HIP_MEMORY_SCOPE_AGENT);
    c = (unsigned)__builtin_amdgcn_readfirstlane((int)pv);
    if (c < tgt) __builtin_amdgcn_s_sleep(2);
  }
  return c;
}

// Repack x [B,T,64] f32 -> f16 B-fragments Xf[g][t][kt][lane][8]
__global__ __launch_bounds__(256) void prep_x(const float* __restrict__ x,
                                              _Float16* __restrict__ Xf) {
  int t0 = blockIdx.x * 256 + threadIdx.x;
  int l = t0 & 63;
  int fid = t0 >> 6;                  // ((g*NT + t)*2 + kt)
  int kt = fid & 1;
  int t = (fid >> 1) & (NT - 1);
  int g = fid >> 11;
  int bt = g * 16 + (l & 15);
  int kb = kt * 32 + (l >> 4) * 4;
  const float* src = x + ((size_t)bt * NT + (size_t)t) * 64 + kb;
  float4 v0 = *(const float4*)src;
  float4 v1 = *(const float4*)(src + 16);
  *(half8*)(Xf + (size_t)fid * 512 + l * 8) = cvt8(v0, v1);
}

// 16 blocks x 512 threads. Blocks 0-7: layer-0 producer; 8-15: layer-1+FC
// consumer (R6 structure). NEW vs R6: every gate acc is computed as TWO
// parallel dependent chains (hh-chain from fresh LDS h + ih/x-chain from
// register operands) summed at the end -> chain depth 4, 8 chains/wave;
// cell uses 4/5-instr sigmoid/tanh.
__global__ __launch_bounds__(512, 1) void lstm_main(
    const float* __restrict__ wih0, const float* __restrict__ whh0,
    const float* __restrict__ wih1, const float* __restrict__ whh1,
    const float* __restrict__ bih, const float* __restrict__ bhh,
    const float* __restrict__ fcw, const float* __restrict__ fcb,
    const _Float16* __restrict__ Xf, _Float16* __restrict__ ringH0,
    unsigned* __restrict__ flags, float* __restrict__ out) {
  const int tid = threadIdx.x;
  const int w = tid >> 6, l = tid & 63;
  const int n = l & 15, lg = l >> 4;
  const bool producer = blockIdx.x < 8;
  const int g = blockIdx.x & 7;

  __shared__ _Float16 hfr[2][4][64][8];   // own-layer h frag ring (8 KB)
  __shared__ _Float16 fcl[4][4][64][8];   // FC A-frags per FC wave (16 KB)

  _Float16* ringG = ringH0 + (size_t)g * RINGS * 2048;
  unsigned* prog = flags + g * 16;        // producer progress
  unsigned* cons = flags + (8 + g) * 16;  // consumer progress
  const half8 hz = {0, 0, 0, 0, 0, 0, 0, 0};

  if (producer) {
    // ---- layer-0: acc = [x-chain 2kt] + [hh-chain 4kt] ----
    half8 A[4][6];
    f32x4 bias[4];
#pragma unroll
    for (int q = 0; q < 4; ++q) {
      int row = (w + 8 * q) * 16 + n;
#pragma unroll
      for (int kt = 0; kt < 2; ++kt) {
        const float* wp = wih0 + (size_t)row * 64 + kt * 32 + lg * 4;
        A[q][kt] = cvt8(*(const float4*)wp, *(const float4*)(wp + 16));
      }
#pragma unroll
      for (int kt = 0; kt < 4; ++kt) {
        const float* wp = whh0 + (size_t)row * 128 + kt * 32 + lg * 4;
        A[q][2 + kt] = cvt8(*(const float4*)wp, *(const float4*)(wp + 16));
      }
      int rb = (w + 8 * q) * 16 + lg * 4;
      f32x4 bv;
#pragma unroll
      for (int r = 0; r < 4; ++r) bv[r] = bih[rb + r] + bhh[rb + r];
      bias[q] = bv;
    }
    if (tid < 256) ((half8*)&hfr[1][0][0][0])[tid] = hz;  // h0[-1]=0
    const _Float16* XfG = Xf + (size_t)g * NT * 1024;
    half8 x0 = *(const half8*)(XfG + l * 8);
    half8 x1 = *(const half8*)(XfG + 512 + l * 8);
    f32x4 cst = {0.f, 0.f, 0.f, 0.f};
    unsigned Cc = 0;
    __syncthreads();
    for (int s = 0; s < NT; ++s) {
      half8 xn0, xn1;
      if (s + 1 < NT) {
        const _Float16* p = XfG + (size_t)(s + 1) * 1024 + l * 8;
        xn0 = *(const half8*)p;
        xn1 = *(const half8*)(p + 512);
      }
      if (s >= 224 && (s & 31) == 0)  // ring backpressure (192-slot lead cap)
        Cc = wpoll(cons, (unsigned)(s - 192), Cc, l);
      const int rdk = (s + 1) & 1;
      half8 b2 = *(const half8*)&hfr[rdk][0][l][0];
      half8 b3 = *(const half8*)&hfr[rdk][1][l][0];
      half8 b4 = *(const half8*)&hfr[rdk][2][l][0];
      half8 b5 = *(const half8*)&hfr[rdk][3][l][0];
      // x-chain (register operands, starts immediately)
      f32x4 xc0 = {0.f, 0.f, 0.f, 0.f}, xc1 = xc0, xc2 = xc0, xc3 = xc0;
      xc0 = MFMA(A[0][0], x0, xc0); xc1 = MFMA(A[1][0], x0, xc1);
      xc2 = MFMA(A[2][0], x0, xc2); xc3 = MFMA(A[3][0], x0, xc3);
      xc0 = MFMA(A[0][1], x1, xc0); xc1 = MFMA(A[1][1], x1, xc1);
      xc2 = MFMA(A[2][1], x1, xc2); xc3 = MFMA(A[3][1], x1, xc3);
      // hh-chain (LDS operands)
      f32x4 hc0 = bias[0], hc1 = bias[1], hc2 = bias[2], hc3 = bias[3];
      hc0 = MFMA(A[0][2], b2, hc0); hc1 = MFMA(A[1][2], b2, hc1);
      hc2 = MFMA(A[2][2], b2, hc2); hc3 = MFMA(A[3][2], b2, hc3);
      hc0 = MFMA(A[0][3], b3, hc0); hc1 = MFMA(A[1][3], b3, hc1);
      hc2 = MFMA(A[2][3], b3, hc2); hc3 = MFMA(A[3][3], b3, hc3);
      hc0 = MFMA(A[0][4], b4, hc0); hc1 = MFMA(A[1][4], b4, hc1);
      hc2 = MFMA(A[2][4], b4, hc2); hc3 = MFMA(A[3][4], b4, hc3);
      hc0 = MFMA(A[0][5], b5, hc0); hc1 = MFMA(A[1][5], b5, hc1);
      hc2 = MFMA(A[2][5], b5, hc2); hc3 = MFMA(A[3][5], b5, hc3);
      f32x4 acc0 = hc0 + xc0, acc1 = hc1 + xc1;
      f32x4 acc2 = hc2 + xc2, acc3 = hc3 + xc3;
      half4 hh;
#pragma unroll
      for (int r = 0; r < 4; ++r) {
        float iv = sigf(acc0[r]), fv = sigf(acc1[r]);
        float gv = tanhf2(acc2[r]), ov = sigf(acc3[r]);
        cst[r] = fv * cst[r] + iv * gv;
        hh[r] = (_Float16)(ov * tanhf2(cst[r]));
      }
      *(half4*)&hfr[s & 1][w >> 1][l][(w & 1) << 2] = hh;
      {  // ring store stays IN FLIGHT across the raw barrier
        u64 uh = __builtin_bit_cast(u64, hh);
        __hip_atomic_store(
            (u64*)(ringG + (size_t)(s & (RINGS - 1)) * 2048 +
                   (w >> 1) * 512 + l * 8 + (w & 1) * 4),
            uh, __ATOMIC_RELAXED, __HIP_MEMORY_SCOPE_AGENT);
      }
      asm volatile("s_waitcnt lgkmcnt(0)" ::: "memory");
      __builtin_amdgcn_sched_barrier(0);
      __builtin_amdgcn_s_barrier();   // vmcnt NOT drained
      __builtin_amdgcn_sched_barrier(0);
      if ((s & 31) == 31) {  // batched publish
        asm volatile("s_waitcnt vmcnt(0)" ::: "memory");
        __builtin_amdgcn_sched_barrier(0);
        __builtin_amdgcn_s_barrier();
        __builtin_amdgcn_sched_barrier(0);
        if (tid == 0)
          __hip_atomic_store(prog, (unsigned)(s + 1), __ATOMIC_RELEASE,
                             __HIP_MEMORY_SCOPE_AGENT);
      }
      x0 = xn0;
      x1 = xn1;
    }
  } else {
    // ---- layer-1 + FC: acc = [ih-chain 4kt, reg operands] + [hh-chain 4kt] --
    half8 A[4][8];
    f32x4 bias[4], fcbv = {0.f, 0.f, 0.f, 0.f};
#pragma unroll
    for (int q = 0; q < 4; ++q) {
      int row = (w + 8 * q) * 16 + n;
#pragma unroll
      for (int kt = 0; kt < 4; ++kt) {
        const float* wp = wih1 + (size_t)row * 128 + kt * 32 + lg * 4;
        A[q][kt] = cvt8(*(const float4*)wp, *(const float4*)(wp + 16));
      }
#pragma unroll
      for (int kt = 0; kt < 4; ++kt) {
        const float* wp = whh1 + (size_t)row * 128 + kt * 32 + lg * 4;
        A[q][4 + kt] = cvt8(*(const float4*)wp, *(const float4*)(wp + 16));
      }
      int rb = (w + 8 * q) * 16 + lg * 4;
      f32x4 bv;
#pragma unroll
      for (int r = 0; r < 4; ++r)
        bv[r] = bih[512 + rb + r] + bhh[512 + rb + r];
      bias[q] = bv;
    }
    if (w < 4) {  // FC A-frags -> LDS
      int frow = (w << 4) + n;
#pragma unroll
      for (int kt = 0; kt < 4; ++kt) {
        const float* wp = fcw + (size_t)frow * 128 + kt * 32 + lg * 4;
        *(half8*)&fcl[w][kt][l][0] =
            cvt8(*(const float4*)wp, *(const float4*)(wp + 16));
      }
      fcbv = *(const f32x4*)(fcb + (w << 4) + lg * 4);
    }
    if (tid < 256) ((half8*)&hfr[1][0][0][0])[tid] = hz;  // h1[-1]=0
    float* outG = out + (size_t)((g << 4) + n) * NT * 64 + (w << 4) + lg * 4;
    f32x4 cst = {0.f, 0.f, 0.f, 0.f};
    __syncthreads();
    unsigned Pc = wpoll(prog, 2u, 0u, l);
    half8 hA0 = ldring(ringG + l * 8);
    half8 hA1 = ldring(ringG + 512 + l * 8);
    half8 hA2 = ldring(ringG + 1024 + l * 8);
    half8 hA3 = ldring(ringG + 1536 + l * 8);
    const _Float16* rb1 = ringG + 2048 + l * 8;
    half8 hB0 = ldring(rb1);
    half8 hB1 = ldring(rb1 + 512);
    half8 hB2 = ldring(rb1 + 1024);
    half8 hB3 = ldring(rb1 + 1536);

#define CSTEP(T, C0, C1, C2, C3)                                               \
  {                                                                            \
    const int rdk_ = ((T) + 1) & 1;                                            \
    half8 b4 = *(const half8*)&hfr[rdk_][0][l][0];                             \
    half8 b5 = *(const half8*)&hfr[rdk_][1][l][0];                             \
    half8 b6 = *(const half8*)&hfr[rdk_][2][l][0];                             \
    half8 b7 = *(const half8*)&hfr[rdk_][3][l][0];                             \
    /* ih-chain: register operands, starts at barrier exit */                  \
    f32x4 ic0 = {0.f, 0.f, 0.f, 0.f}, ic1 = ic0, ic2 = ic0, ic3 = ic0;         \
    ic0 = MFMA(A[0][0], C0, ic0); ic1 = MFMA(A[1][0], C0, ic1);                \
    ic2 = MFMA(A[2][0], C0, ic2); ic3 = MFMA(A[3][0], C0, ic3);                \
    ic0 = MFMA(A[0][1], C1, ic0); ic1 = MFMA(A[1][1], C1, ic1);                \
    ic2 = MFMA(A[2][1], C1, ic2); ic3 = MFMA(A[3][1], C1, ic3);                \
    ic0 = MFMA(A[0][2], C2, ic0); ic1 = MFMA(A[1][2], C2, ic1);                \
    ic2 = MFMA(A[2][2], C2, ic2); ic3 = MFMA(A[3][2], C2, ic3);                \
    ic0 = MFMA(A[0][3], C3, ic0); ic1 = MFMA(A[1][3], C3, ic1);                \
    ic2 = MFMA(A[2][3], C3, ic2); ic3 = MFMA(A[3][3], C3, ic3);                \
    if ((T) + 2 < NT) { /* reload CUR with h0[T+2]; flies across barriers */   \
      Pc = wpoll(prog, (unsigned)((T) + 3), Pc, l);                            \
      const _Float16* rb_ =                                                    \
          ringG + (size_t)(((T) + 2) & (RINGS - 1)) * 2048 + l * 8;            \
      C0 = ldring(rb_);        C1 = ldring(rb_ + 512);                         \
      C2 = ldring(rb_ + 1024); C3 = ldring(rb_ + 1536);                        \
    }                                                                          \
    /* hh-chain: LDS operands */                                               \
    f32x4 hc0 = bias[0], hc1 = bias[1], hc2 = bias[2], hc3 = bias[3];          \
    hc0 = MFMA(A[0][4], b4, hc0); hc1 = MFMA(A[1][4], b4, hc1);                \
    hc2 = MFMA(A[2][4], b4, hc2); hc3 = MFMA(A[3][4], b4, hc3);                \
    hc0 = MFMA(A[0][5], b5, hc0); hc1 = MFMA(A[1][5], b5, hc1);                \
    hc2 = MFMA(A[2][5], b5, hc2); hc3 = MFMA(A[3][5], b5, hc3);                \
    hc0 = MFMA(A[0][6], b6, hc0); hc1 = MFMA(A[1][6], b6, hc1);                \
    hc2 = MFMA(A[2][6], b6, hc2); hc3 = MFMA(A[3][6], b6, hc3);                \
    hc0 = MFMA(A[0][7], b7, hc0); hc1 = MFMA(A[1][7], b7, hc1);                \
    hc2 = MFMA(A[2][7], b7, hc2); hc3 = MFMA(A[3][7], b7, hc3);                \
    if (w < 4) { /* FC of h1[T-1] on same operands */                          \
      half8 f0 = *(const half8*)&fcl[w][0][l][0];                              \
      half8 f1 = *(const half8*)&fcl[w][1][l][0];                              \
      half8 f2 = *(const half8*)&fcl[w][2][l][0];                              \
      half8 f3 = *(const half8*)&fcl[w][3][l][0];                              \
      f32x4 afc = fcbv;                                                        \
      afc = MFMA(f0, b4, afc); afc = MFMA(f1, b5, afc);                        \
      afc = MFMA(f2, b6, afc); afc = MFMA(f3, b7, afc);                        \
      if ((T) >= 1) *(f32x4*)(outG + (size_t)((T) - 1) * 64) = afc;            \
    }                                                                          \
    f32x4 acc0 = hc0 + ic0, acc1 = hc1 + ic1;                                  \
    f32x4 acc2 = hc2 + ic2, acc3 = hc3 + ic3;                                  \
    half4 hh;                                                                  \
    _Pragma("unroll")                                                          \
    for (int r = 0; r < 4; ++r) {                                              \
      float iv = sigf(acc0[r]), fv = sigf(acc1[r]);                            \
      float gv = tanhf2(acc2[r]), ov = sigf(acc3[r]);                          \
      cst[r] = fv * cst[r] + iv * gv;                                          \
      hh[r] = (_Float16)(ov * tanhf2(cst[r]));                                 \
    }                                                                          \
    *(half4*)&hfr[(T) & 1][w >> 1][l][(w & 1) << 2] = hh;                      \
    if (tid == 0 && ((T) & 31) == 0)                                           \
      __hip_atomic_store(cons, (unsigned)(T), __ATOMIC_RELAXED,                \
                         __HIP_MEMORY_SCOPE_AGENT);                            \
    asm volatile("s_waitcnt lgkmcnt(0)" ::: "memory");                         \
    __builtin_amdgcn_sched_barrier(0);                                         \
    __builtin_amdgcn_s_barrier(); /* h0 prefetch stays in flight */            \
    __builtin_amdgcn_sched_barrier(0);                                         \
  }

    for (int t = 0; t < NT; t += 2) {
      CSTEP(t, hA0, hA1, hA2, hA3);
      CSTEP(t + 1, hB0, hB1, hB2, hB3);
    }
#undef CSTEP
    {  // epilogue: FC of h1[NT-1] -> out[NT-1]
      half8 b4 = *(const half8*)&hfr[(NT + 1) & 1][0][l][0];
      half8 b5 = *(const half8*)&hfr[(NT + 1) & 1][1][l][0];
      half8 b6 = *(const half8*)&hfr[(NT + 1) & 1][2][l][0];
      half8 b7 = *(const half8*)&hfr[(NT + 1) & 1][3][l][0];
      if (w < 4) {
        half8 f0 = *(const half8*)&fcl[w][0][l][0];
        half8 f1 = *(const half8*)&fcl[w][1][l][0];
        half8 f2 = *(const half8*)&fcl[w][2][l][0];
        half8 f3 = *(const half8*)&fcl[w][3][l][0];
        f32x4 afc = fcbv;
        afc = MFMA(f0, b4, afc); afc = MFMA(f1, b5, afc);
        afc = MFMA(f2, b6, afc); afc = MFMA(f3, b7, afc);
        *(f32x4*)(outG + (size_t)(NT - 1) * 64) = afc;
      }
    }
  }
}

extern "C" void kernel_launch(void* const* d_in, const int* in_sizes, int n_in,
                              void* d_out, int out_size, void* d_ws, size_t ws_size,
                              hipStream_t stream) {
  const float* x     = (const float*)d_in[0];
  const float* w_ih0 = (const float*)d_in[1];
  const float* w_hh0 = (const float*)d_in[2];
  const float* w_ih1 = (const float*)d_in[3];
  const float* w_hh1 = (const float*)d_in[4];
  const float* b_ih  = (const float*)d_in[5];
  const float* b_hh  = (const float*)d_in[6];
  const float* fc_w  = (const float*)d_in[7];
  const float* fc_b  = (const float*)d_in[8];

  _Float16* Xf   = (_Float16*)d_ws;                           // 16 MB
  _Float16* ring = (_Float16*)((char*)d_ws + (16u << 20));    // 8 MB
  unsigned* flags = (unsigned*)((char*)d_ws + (24u << 20));   // 4 KB

  hipMemsetAsync(flags, 0, 4096, stream);
  prep_x<<<4096, 256, 0, stream>>>(x, Xf);
  lstm_main<<<16, 512, 0, stream>>>(w_ih0, w_hh0, w_ih1, w_hh1, b_ih, b_hh,
                                    fc_w, fc_b, Xf, ring, flags,
                                    (float*)d_out);
}

// Round 10
// 1327.934 us; speedup vs baseline: 1.4960x; 1.0070x over previous
//
#include <hip/hip_runtime.h>

#define NT 1024
#define RINGS 256

typedef _Float16 half8 __attribute__((ext_vector_type(8)));
typedef _Float16 half4 __attribute__((ext_vector_type(4)));
typedef float f32x4 __attribute__((ext_vector_type(4)));
typedef unsigned long long u64;
struct U2 { u64 a, b; };

#ifndef __has_builtin
#define __has_builtin(x) 0
#endif

__device__ __forceinline__ f32x4 MFMA(half8 a, half8 b, f32x4 c) {
  return __builtin_amdgcn_mfma_f32_16x16x32_f16(a, b, c, 0, 0, 0);
}
__device__ __forceinline__ float exp2h(float x) {
#if __has_builtin(__builtin_amdgcn_exp2f)
  return __builtin_amdgcn_exp2f(x);
#else
  return exp2f(x);
#endif
}
__device__ __forceinline__ float sigf(float x) {
  return __builtin_amdgcn_rcpf(1.0f + exp2h(x * -1.44269504f));
}
__device__ __forceinline__ float tanhf2(float x) {
  float t = __builtin_amdgcn_rcpf(1.0f + exp2h(x * 2.88539008f));
  return fmaf(-2.0f, t, 1.0f);
}
__device__ __forceinline__ half8 cvt8(float4 c0, float4 c1) {
  half8 hv;
  hv[0] = (_Float16)c0.x; hv[1] = (_Float16)c0.y;
  hv[2] = (_Float16)c0.z; hv[3] = (_Float16)c0.w;
  hv[4] = (_Float16)c1.x; hv[5] = (_Float16)c1.y;
  hv[6] = (_Float16)c1.z; hv[7] = (_Float16)c1.w;
  return hv;
}
__device__ __forceinline__ half8 ldring(const _Float16* p) {
  const u64* q = (const u64*)p;
  U2 uu;
  uu.a = __hip_atomic_load(q, __ATOMIC_RELAXED, __HIP_MEMORY_SCOPE_AGENT);
  uu.b = __hip_atomic_load(q + 1, __ATOMIC_RELAXED, __HIP_MEMORY_SCOPE_AGENT);
  return __builtin_bit_cast(half8, uu);
}
__device__ __forceinline__ unsigned wpoll(unsigned* p, unsigned tgt,
                                          unsigned cached, int l) {
  unsigned c = cached;
  while (c < tgt) {
    unsigned pv = 0;
    if (l == 0)
      pv = __hip_atomic_load(p, __ATOMIC_ACQUIRE, __HIP_MEMORY_SCOPE_AGENT);
    c = (unsigned)__builtin_amdgcn_readfirstlane((int)pv);
    if (c < tgt) __builtin_amdgcn_s_sleep(2);
  }
  return c;
}

// Repack x [B,T,64] f32 -> f16 B-fragments Xf[g][t][kt][lane][8]
__global__ __launch_bounds__(256) void prep_x(const float* __restrict__ x,
                                              _Float16* __restrict__ Xf) {
  int t0 = blockIdx.x * 256 + threadIdx.x;
  int l = t0 & 63;
  int fid = t0 >> 6;                  // ((g*NT + t)*2 + kt)
  int kt = fid & 1;
  int t = (fid >> 1) & (NT - 1);
  int g = fid >> 11;
  int bt = g * 16 + (l & 15);
  int kb = kt * 32 + (l >> 4) * 4;
  const float* src = x + ((size_t)bt * NT + (size_t)t) * 64 + kb;
  float4 v0 = *(const float4*)src;
  float4 v1 = *(const float4*)(src + 16);
  *(half8*)(Xf + (size_t)fid * 512 + l * 8) = cvt8(v0, v1);
}

// 16 blocks x 512 threads; R6 handshake. NEW: the input-side GEMM for step
// t+1 (register/x/ring operands, independent of h[t]) is issued in step t
// right before the cell VALU -> matrix pipe overlaps trans/VALU cell work.
// hh-chain for step t initializes its accumulator from the saved input-side
// result (bias folded in).
__global__ __launch_bounds__(512, 1) void lstm_main(
    const float* __restrict__ wih0, const float* __restrict__ whh0,
    const float* __restrict__ wih1, const float* __restrict__ whh1,
    const float* __restrict__ bih, const float* __restrict__ bhh,
    const float* __restrict__ fcw, const float* __restrict__ fcb,
    const _Float16* __restrict__ Xf, _Float16* __restrict__ ringH0,
    unsigned* __restrict__ flags, float* __restrict__ out) {
  const int tid = threadIdx.x;
  const int w = tid >> 6, l = tid & 63;
  const int n = l & 15, lg = l >> 4;
  const bool producer = blockIdx.x < 8;
  const int g = blockIdx.x & 7;

  __shared__ _Float16 hfr[2][4][64][8];   // own-layer h frag ring (8 KB)
  __shared__ _Float16 fcl[4][4][64][8];   // FC A-frags per FC wave (16 KB)

  _Float16* ringG = ringH0 + (size_t)g * RINGS * 2048;
  unsigned* prog = flags + g * 16;        // producer progress
  unsigned* cons = flags + (8 + g) * 16;  // consumer progress
  const half8 hz = {0, 0, 0, 0, 0, 0, 0, 0};

  if (producer) {
    // ---- layer-0 ----
    half8 A[4][6];
    f32x4 bias[4];
#pragma unroll
    for (int q = 0; q < 4; ++q) {
      int row = (w + 8 * q) * 16 + n;
#pragma unroll
      for (int kt = 0; kt < 2; ++kt) {
        const float* wp = wih0 + (size_t)row * 64 + kt * 32 + lg * 4;
        A[q][kt] = cvt8(*(const float4*)wp, *(const float4*)(wp + 16));
      }
#pragma unroll
      for (int kt = 0; kt < 4; ++kt) {
        const float* wp = whh0 + (size_t)row * 128 + kt * 32 + lg * 4;
        A[q][2 + kt] = cvt8(*(const float4*)wp, *(const float4*)(wp + 16));
      }
      int rb = (w + 8 * q) * 16 + lg * 4;
      f32x4 bv;
#pragma unroll
      for (int r = 0; r < 4; ++r) bv[r] = bih[rb + r] + bhh[rb + r];
      bias[q] = bv;
    }
    if (tid < 256) ((half8*)&hfr[1][0][0][0])[tid] = hz;  // h0[-1]=0
    const _Float16* XfG = Xf + (size_t)g * NT * 1024;
    f32x4 cst = {0.f, 0.f, 0.f, 0.f};
    unsigned Cc = 0;
    // prologue: xs = bias + Wih0 x[0]; xC = x[1] frags
    half8 x0 = *(const half8*)(XfG + l * 8);
    half8 x1 = *(const half8*)(XfG + 512 + l * 8);
    f32x4 xs0 = MFMA(A[0][0], x0, bias[0]);
    f32x4 xs1 = MFMA(A[1][0], x0, bias[1]);
    f32x4 xs2 = MFMA(A[2][0], x0, bias[2]);
    f32x4 xs3 = MFMA(A[3][0], x0, bias[3]);
    xs0 = MFMA(A[0][1], x1, xs0); xs1 = MFMA(A[1][1], x1, xs1);
    xs2 = MFMA(A[2][1], x1, xs2); xs3 = MFMA(A[3][1], x1, xs3);
    half8 xC0 = *(const half8*)(XfG + 1024 + l * 8);
    half8 xC1 = *(const half8*)(XfG + 1024 + 512 + l * 8);
    __syncthreads();
    for (int s = 0; s < NT; ++s) {
      if (s >= 224 && (s & 31) == 0)  // ring backpressure (192-slot lead cap)
        Cc = wpoll(cons, (unsigned)(s - 192), Cc, l);
      // ---- A: hh-chain(s), acc init = saved input-side (bias folded) ----
      const int rdk = (s + 1) & 1;
      half8 b2 = *(const half8*)&hfr[rdk][0][l][0];
      half8 b3 = *(const half8*)&hfr[rdk][1][l][0];
      half8 b4 = *(const half8*)&hfr[rdk][2][l][0];
      half8 b5 = *(const half8*)&hfr[rdk][3][l][0];
      f32x4 hc0 = MFMA(A[0][2], b2, xs0);
      f32x4 hc1 = MFMA(A[1][2], b2, xs1);
      f32x4 hc2 = MFMA(A[2][2], b2, xs2);
      f32x4 hc3 = MFMA(A[3][2], b2, xs3);
      hc0 = MFMA(A[0][3], b3, hc0); hc1 = MFMA(A[1][3], b3, hc1);
      hc2 = MFMA(A[2][3], b3, hc2); hc3 = MFMA(A[3][3], b3, hc3);
      hc0 = MFMA(A[0][4], b4, hc0); hc1 = MFMA(A[1][4], b4, hc1);
      hc2 = MFMA(A[2][4], b4, hc2); hc3 = MFMA(A[3][4], b4, hc3);
      hc0 = MFMA(A[0][5], b5, hc0); hc1 = MFMA(A[1][5], b5, hc1);
      hc2 = MFMA(A[2][5], b5, hc2); hc3 = MFMA(A[3][5], b5, hc3);
      // ---- B: x-chain(s+1) on matrix pipe, overlaps the cell below ----
      if (s + 1 < NT) {
        xs0 = MFMA(A[0][0], xC0, bias[0]);
        xs1 = MFMA(A[1][0], xC0, bias[1]);
        xs2 = MFMA(A[2][0], xC0, bias[2]);
        xs3 = MFMA(A[3][0], xC0, bias[3]);
        xs0 = MFMA(A[0][1], xC1, xs0); xs1 = MFMA(A[1][1], xC1, xs1);
        xs2 = MFMA(A[2][1], xC1, xs2); xs3 = MFMA(A[3][1], xC1, xs3);
      }
      if (s + 2 < NT) {  // reload xC with x[s+2] (plain loads, 1-step cover)
        const _Float16* p = XfG + (size_t)(s + 2) * 1024 + l * 8;
        xC0 = *(const half8*)p;
        xC1 = *(const half8*)(p + 512);
      }
      // ---- cell(s) ----
      half4 hh;
#pragma unroll
      for (int r = 0; r < 4; ++r) {
        float iv = sigf(hc0[r]), fv = sigf(hc1[r]);
        float gv = tanhf2(hc2[r]), ov = sigf(hc3[r]);
        cst[r] = fv * cst[r] + iv * gv;
        hh[r] = (_Float16)(ov * tanhf2(cst[r]));
      }
      *(half4*)&hfr[s & 1][w >> 1][l][(w & 1) << 2] = hh;
      {  // ring store stays IN FLIGHT across the raw barrier
        u64 uh = __builtin_bit_cast(u64, hh);
        __hip_atomic_store(
            (u64*)(ringG + (size_t)(s & (RINGS - 1)) * 2048 +
                   (w >> 1) * 512 + l * 8 + (w & 1) * 4),
            uh, __ATOMIC_RELAXED, __HIP_MEMORY_SCOPE_AGENT);
      }
      asm volatile("s_waitcnt lgkmcnt(0)" ::: "memory");
      __builtin_amdgcn_sched_barrier(0);
      __builtin_amdgcn_s_barrier();   // vmcnt NOT drained
      __builtin_amdgcn_sched_barrier(0);
      if ((s & 31) == 31) {  // batched drained publish
        asm volatile("s_waitcnt vmcnt(0)" ::: "memory");
        __builtin_amdgcn_sched_barrier(0);
        __builtin_amdgcn_s_barrier();
        __builtin_amdgcn_sched_barrier(0);
        if (tid == 0)
          __hip_atomic_store(prog, (unsigned)(s + 1), __ATOMIC_RELEASE,
                             __HIP_MEMORY_SCOPE_AGENT);
      }
    }
  } else {
    // ---- layer-1 + FC ----
    half8 A[4][8];
    f32x4 bias[4], fcbv = {0.f, 0.f, 0.f, 0.f};
#pragma unroll
    for (int q = 0; q < 4; ++q) {
      int row = (w + 8 * q) * 16 + n;
#pragma unroll
      for (int kt = 0; kt < 4; ++kt) {
        const float* wp = wih1 + (size_t)row * 128 + kt * 32 + lg * 4;
        A[q][kt] = cvt8(*(const float4*)wp, *(const float4*)(wp + 16));
      }
#pragma unroll
      for (int kt = 0; kt < 4; ++kt) {
        const float* wp = whh1 + (size_t)row * 128 + kt * 32 + lg * 4;
        A[q][4 + kt] = cvt8(*(const float4*)wp, *(const float4*)(wp + 16));
      }
      int rb = (w + 8 * q) * 16 + lg * 4;
      f32x4 bv;
#pragma unroll
      for (int r = 0; r < 4; ++r)
        bv[r] = bih[512 + rb + r] + bhh[512 + rb + r];
      bias[q] = bv;
    }
    if (w < 4) {  // FC A-frags -> LDS
      int frow = (w << 4) + n;
#pragma unroll
      for (int kt = 0; kt < 4; ++kt) {
        const float* wp = fcw + (size_t)frow * 128 + kt * 32 + lg * 4;
        *(half8*)&fcl[w][kt][l][0] =
            cvt8(*(const float4*)wp, *(const float4*)(wp + 16));
      }
      fcbv = *(const f32x4*)(fcb + (w << 4) + lg * 4);
    }
    if (tid < 256) ((half8*)&hfr[1][0][0][0])[tid] = hz;  // h1[-1]=0
    float* outG = out + (size_t)((g << 4) + n) * NT * 64 + (w << 4) + lg * 4;
    f32x4 cst = {0.f, 0.f, 0.f, 0.f};
    __syncthreads();
    // prologue: is = bias + Wih1 h0[0]; HC = h0[1] frags
    unsigned Pc = wpoll(prog, 2u, 0u, l);
    half8 t0 = ldring(ringG + l * 8);
    half8 t1 = ldring(ringG + 512 + l * 8);
    half8 t2 = ldring(ringG + 1024 + l * 8);
    half8 t3 = ldring(ringG + 1536 + l * 8);
    f32x4 is0 = MFMA(A[0][0], t0, bias[0]);
    f32x4 is1 = MFMA(A[1][0], t0, bias[1]);
    f32x4 is2 = MFMA(A[2][0], t0, bias[2]);
    f32x4 is3 = MFMA(A[3][0], t0, bias[3]);
    is0 = MFMA(A[0][1], t1, is0); is1 = MFMA(A[1][1], t1, is1);
    is2 = MFMA(A[2][1], t1, is2); is3 = MFMA(A[3][1], t1, is3);
    is0 = MFMA(A[0][2], t2, is0); is1 = MFMA(A[1][2], t2, is1);
    is2 = MFMA(A[2][2], t2, is2); is3 = MFMA(A[3][2], t2, is3);
    is0 = MFMA(A[0][3], t3, is0); is1 = MFMA(A[1][3], t3, is1);
    is2 = MFMA(A[2][3], t3, is2); is3 = MFMA(A[3][3], t3, is3);
    const _Float16* rb1 = ringG + 2048 + l * 8;
    half8 HC0 = ldring(rb1);
    half8 HC1 = ldring(rb1 + 512);
    half8 HC2 = ldring(rb1 + 1024);
    half8 HC3 = ldring(rb1 + 1536);
    for (int t = 0; t < NT; ++t) {
      // ---- A: hh-chain(t) init = saved input-side; FC of h1[t-1] ----
      const int rdk = (t + 1) & 1;
      half8 b4 = *(const half8*)&hfr[rdk][0][l][0];
      half8 b5 = *(const half8*)&hfr[rdk][1][l][0];
      half8 b6 = *(const half8*)&hfr[rdk][2][l][0];
      half8 b7 = *(const half8*)&hfr[rdk][3][l][0];
      f32x4 hc0 = MFMA(A[0][4], b4, is0);
      f32x4 hc1 = MFMA(A[1][4], b4, is1);
      f32x4 hc2 = MFMA(A[2][4], b4, is2);
      f32x4 hc3 = MFMA(A[3][4], b4, is3);
      hc0 = MFMA(A[0][5], b5, hc0); hc1 = MFMA(A[1][5], b5, hc1);
      hc2 = MFMA(A[2][5], b5, hc2); hc3 = MFMA(A[3][5], b5, hc3);
      hc0 = MFMA(A[0][6], b6, hc0); hc1 = MFMA(A[1][6], b6, hc1);
      hc2 = MFMA(A[2][6], b6, hc2); hc3 = MFMA(A[3][6], b6, hc3);
      hc0 = MFMA(A[0][7], b7, hc0); hc1 = MFMA(A[1][7], b7, hc1);
      hc2 = MFMA(A[2][7], b7, hc2); hc3 = MFMA(A[3][7], b7, hc3);
      if (w < 4) {  // FC of h1[t-1] on same operands
        half8 f0 = *(const half8*)&fcl[w][0][l][0];
        half8 f1 = *(const half8*)&fcl[w][1][l][0];
        half8 f2 = *(const half8*)&fcl[w][2][l][0];
        half8 f3 = *(const half8*)&fcl[w][3][l][0];
        f32x4 afc = fcbv;
        afc = MFMA(f0, b4, afc); afc = MFMA(f1, b5, afc);
        afc = MFMA(f2, b6, afc); afc = MFMA(f3, b7, afc);
        if (t >= 1) *(f32x4*)(outG + (size_t)(t - 1) * 64) = afc;
      }
      // ---- B: ih-chain(t+1) on matrix pipe, overlaps the cell below ----
      if (t + 1 < NT) {
        is0 = MFMA(A[0][0], HC0, bias[0]);
        is1 = MFMA(A[1][0], HC0, bias[1]);
        is2 = MFMA(A[2][0], HC0, bias[2]);
        is3 = MFMA(A[3][0], HC0, bias[3]);
        is0 = MFMA(A[0][1], HC1, is0); is1 = MFMA(A[1][1], HC1, is1);
        is2 = MFMA(A[2][1], HC1, is2); is3 = MFMA(A[3][1], HC1, is3);
        is0 = MFMA(A[0][2], HC2, is0); is1 = MFMA(A[1][2], HC2, is1);
        is2 = MFMA(A[2][2], HC2, is2); is3 = MFMA(A[3][2], HC2, is3);
        is0 = MFMA(A[0][3], HC3, is0); is1 = MFMA(A[1][3], HC3, is1);
        is2 = MFMA(A[2][3], HC3, is2); is3 = MFMA(A[3][3], HC3, is3);
      }
      if (t + 2 < NT) {  // reload HC with h0[t+2]; ~1 full step of cover
        Pc = wpoll(prog, (unsigned)(t + 3), Pc, l);
        const _Float16* rb_ =
            ringG + (size_t)((t + 2) & (RINGS - 1)) * 2048 + l * 8;
        HC0 = ldring(rb_);
        HC1 = ldring(rb_ + 512);
        HC2 = ldring(rb_ + 1024);
        HC3 = ldring(rb_ + 1536);
      }
      // ---- cell(t) ----
      half4 hh;
#pragma unroll
      for (int r = 0; r < 4; ++r) {
        float iv = sigf(hc0[r]), fv = sigf(hc1[r]);
        float gv = tanhf2(hc2[r]), ov = sigf(hc3[r]);
        cst[r] = fv * cst[r] + iv * gv;
        hh[r] = (_Float16)(ov * tanhf2(cst[r]));
      }
      *(half4*)&hfr[t & 1][w >> 1][l][(w & 1) << 2] = hh;
      if (tid == 0 && (t & 31) == 0)
        __hip_atomic_store(cons, (unsigned)t, __ATOMIC_RELAXED,
                           __HIP_MEMORY_SCOPE_AGENT);
      asm volatile("s_waitcnt lgkmcnt(0)" ::: "memory");
      __builtin_amdgcn_sched_barrier(0);
      __builtin_amdgcn_s_barrier();  // ring prefetch stays in flight
      __builtin_amdgcn_sched_barrier(0);
    }
    {  // epilogue: FC of h1[NT-1] -> out[NT-1]
      half8 b4 = *(const half8*)&hfr[(NT + 1) & 1][0][l][0];
      half8 b5 = *(const half8*)&hfr[(NT + 1) & 1][1][l][0];
      half8 b6 = *(const half8*)&hfr[(NT + 1) & 1][2][l][0];
      half8 b7 = *(const half8*)&hfr[(NT + 1) & 1][3][l][0];
      if (w < 4) {
        half8 f0 = *(const half8*)&fcl[w][0][l][0];
        half8 f1 = *(const half8*)&fcl[w][1][l][0];
        half8 f2 = *(const half8*)&fcl[w][2][l][0];
        half8 f3 = *(const half8*)&fcl[w][3][l][0];
        f32x4 afc = fcbv;
        afc = MFMA(f0, b4, afc); afc = MFMA(f1, b5, afc);
        afc = MFMA(f2, b6, afc); afc = MFMA(f3, b7, afc);
        *(f32x4*)(outG + (size_t)(NT - 1) * 64) = afc;
      }
    }
  }
}

extern "C" void kernel_launch(void* const* d_in, const int* in_sizes, int n_in,
                              void* d_out, int out_size, void* d_ws, size_t ws_size,
                              hipStream_t stream) {
  const float* x     = (const float*)d_in[0];
  const float* w_ih0 = (const float*)d_in[1];
  const float* w_hh0 = (const float*)d_in[2];
  const float* w_ih1 = (const float*)d_in[3];
  const float* w_hh1 = (const float*)d_in[4];
  const float* b_ih  = (const float*)d_in[5];
  const float* b_hh  = (const float*)d_in[6];
  const float* fc_w  = (const float*)d_in[7];
  const float* fc_b  = (const float*)d_in[8];

  _Float16* Xf   = (_Float16*)d_ws;                           // 16 MB
  _Float16* ring = (_Float16*)((char*)d_ws + (16u << 20));    // 8 MB
  unsigned* flags = (unsigned*)((char*)d_ws + (24u << 20));   // 4 KB

  hipMemsetAsync(flags, 0, 4096, stream);
  prep_x<<<4096, 256, 0, stream>>>(x, Xf);
  lstm_main<<<16, 512, 0, stream>>>(w_ih0, w_hh0, w_ih1, w_hh1, b_ih, b_hh,
                                    fc_w, fc_b, Xf, ring, flags,
                                    (float*)d_out);
}